// Round 9
// baseline (13840.387 us; speedup 1.0000x reference)
//
#include <hip/hip_runtime.h>

// Reservoir forward, R9 = R6 + joint-spin poll + 4-way split accumulators.
//   Epoch-tagged u64 state exchange (value|epoch) via relaxed agent-scope
//   atomics resolving at the Infinity Cache. 128 wgs x 512 thr, 2 rows/wave,
//   W in VGPRs (64 regs/thread).
//   R8 lesson: replicated publish = line-scattered IF writes = regression.
//   R9 attacks two serial cascades in R6:
//     (1) sequential while(p0);while(p1);... -> joint spin (wait = max not sum)
//     (2) 64-deep dependent FMA chain -> 4 partial accumulators per row.

typedef unsigned long long u64;

#define NRES 2048
#define NIN  64
#define NOUT 16
#define TT   4096
#define GWG  128           // workgroups
#define BTH  512           // threads per wg (8 waves)
#define ROWS_PER_WG 16     // NRES / GWG, 2 rows per wave
#define NJ 8               // float4 blocks per lane (32 cols)

__global__ void init_ws(u64* statebuf) {
    int i = blockIdx.x * blockDim.x + threadIdx.x;
    if (i < NRES)            statebuf[i] = 0ull;                   // buf0: epoch 0, value 0
    else if (i < 2 * NRES)   statebuf[i] = 0xFFFFFFFF00000000ull;  // buf1: invalid epoch
}

__launch_bounds__(BTH, 2)   // VGPR cap 256; W (64 regs) + partials fit
__global__ void reservoir_run(const float* __restrict__ inputs,
                              const float* __restrict__ outputs,
                              const float* __restrict__ noise,
                              const float* __restrict__ w,
                              const float* __restrict__ w_in,
                              const float* __restrict__ w_feedb,
                              u64* statebuf)
{
    const int wg   = blockIdx.x;      // 0..127
    const int tid  = threadIdx.x;     // 0..511
    const int wave = tid >> 6;        // 0..7
    const int lane = tid & 63;
    const int row0 = wg * ROWS_PER_WG + wave * 2;   // wave owns rows row0, row0+1

    // ---- W rows into VGPRs: 2 rows x 8 float4 = 64 regs/thread ----
    const float4* wr0 = (const float4*)(w + (size_t)(row0 + 0) * NRES);
    const float4* wr1 = (const float4*)(w + (size_t)(row0 + 1) * NRES);
    float4 wv0[NJ], wv1[NJ];
#pragma unroll
    for (int j = 0; j < NJ; ++j) {
        wv0[j] = wr0[64 * j + lane];
        wv1[j] = wr1[64 * j + lane];
    }
    // pin: block rematerialization (R3's failure mode)
#pragma unroll
    for (int j = 0; j < NJ; ++j) {
        asm volatile("" : "+v"(wv0[j].x), "+v"(wv0[j].y), "+v"(wv0[j].z), "+v"(wv0[j].w));
        asm volatile("" : "+v"(wv1[j].x), "+v"(wv1[j].y), "+v"(wv1[j].z), "+v"(wv1[j].w));
    }
    const float wi0 = w_in[(row0 + 0) * NIN + lane];
    const float wi1 = w_in[(row0 + 1) * NIN + lane];
    const float wf0 = (lane < NOUT) ? w_feedb[(row0 + 0) * NOUT + lane] : 0.0f;
    const float wf1 = (lane < NOUT) ? w_feedb[(row0 + 1) * NOUT + lane] : 0.0f;

    __shared__ float s_state[2][NRES];   // 16 KB parity double buffer

    // software-pipelined externals
    float inp_c = inputs[1 * NIN + lane];
    float po_c  = (lane < NOUT) ? outputs[0 * NOUT + lane] : 0.0f;
    float nz_c  = (lane < 2) ? noise[(size_t)1 * NRES + row0 + lane] : 0.0f;

    for (int t = 1; t < TT; ++t) {
        const u64* sbuf = statebuf + ((t - 1) & 1) * NRES;
        u64*       dbuf = statebuf + (t & 1) * NRES;
        float*     sl   = s_state[(t - 1) & 1];
        const unsigned want = (unsigned)(t - 1);

        const float b0 = fmaf(wf0, po_c, wi0 * inp_c);
        const float b1 = fmaf(wf1, po_c, wi1 * inp_c);
        const float nz = nz_c;

        // ---- joint-spin poll of 4 u64: wait = max over words, not sum ----
        u64 p0 = __hip_atomic_load(&sbuf[tid],        __ATOMIC_RELAXED, __HIP_MEMORY_SCOPE_AGENT);
        u64 p1 = __hip_atomic_load(&sbuf[tid +  512], __ATOMIC_RELAXED, __HIP_MEMORY_SCOPE_AGENT);
        u64 p2 = __hip_atomic_load(&sbuf[tid + 1024], __ATOMIC_RELAXED, __HIP_MEMORY_SCOPE_AGENT);
        u64 p3 = __hip_atomic_load(&sbuf[tid + 1536], __ATOMIC_RELAXED, __HIP_MEMORY_SCOPE_AGENT);
        for (;;) {
            bool ok0 = ((unsigned)(p0 >> 32) == want);
            bool ok1 = ((unsigned)(p1 >> 32) == want);
            bool ok2 = ((unsigned)(p2 >> 32) == want);
            bool ok3 = ((unsigned)(p3 >> 32) == want);
            if (ok0 & ok1 & ok2 & ok3) break;
            // re-issue only stale words, back-to-back (all in flight together)
            if (!ok0) p0 = __hip_atomic_load(&sbuf[tid],        __ATOMIC_RELAXED, __HIP_MEMORY_SCOPE_AGENT);
            if (!ok1) p1 = __hip_atomic_load(&sbuf[tid +  512], __ATOMIC_RELAXED, __HIP_MEMORY_SCOPE_AGENT);
            if (!ok2) p2 = __hip_atomic_load(&sbuf[tid + 1024], __ATOMIC_RELAXED, __HIP_MEMORY_SCOPE_AGENT);
            if (!ok3) p3 = __hip_atomic_load(&sbuf[tid + 1536], __ATOMIC_RELAXED, __HIP_MEMORY_SCOPE_AGENT);
        }
        sl[tid]        = __uint_as_float((unsigned)p0);
        sl[tid +  512] = __uint_as_float((unsigned)p1);
        sl[tid + 1024] = __uint_as_float((unsigned)p2);
        sl[tid + 1536] = __uint_as_float((unsigned)p3);
        __syncthreads();

        // prefetch next step's externals (hide under FMA phase)
        if (t + 1 < TT) {
            inp_c = inputs[(t + 1) * NIN + lane];
            po_c  = (lane < NOUT) ? outputs[t * NOUT + lane] : 0.0f;
            nz_c  = (lane < 2) ? noise[(size_t)(t + 1) * NRES + row0 + lane] : 0.0f;
        }

        // ---- 2 row dot-products, 4 partial accumulators each (chains of 16) ----
        const float4* s4 = (const float4*)sl;
        float a00 = 0.f, a01 = 0.f, a02 = 0.f, a03 = 0.f;
        float a10 = 0.f, a11 = 0.f, a12 = 0.f, a13 = 0.f;
#pragma unroll
        for (int j = 0; j < NJ; ++j) {
            float4 sv = s4[64 * j + lane];
            a00 = fmaf(wv0[j].x, sv.x, a00); a01 = fmaf(wv0[j].y, sv.y, a01);
            a02 = fmaf(wv0[j].z, sv.z, a02); a03 = fmaf(wv0[j].w, sv.w, a03);
            a10 = fmaf(wv1[j].x, sv.x, a10); a11 = fmaf(wv1[j].y, sv.y, a11);
            a12 = fmaf(wv1[j].z, sv.z, a12); a13 = fmaf(wv1[j].w, sv.w, a13);
        }
        float a0 = b0 + ((a00 + a01) + (a02 + a03));
        float a1 = b1 + ((a10 + a11) + (a12 + a13));

        // ---- paired reduction: 6 shuffles; even lanes -> a0 sum, odd -> a1 ----
        float c = (lane & 1) ? a1 : a0;
        float d = (lane & 1) ? a0 : a1;
        c += __shfl_xor(d, 1, 64);
#pragma unroll
        for (int off = 2; off <= 32; off <<= 1) c += __shfl_xor(c, off, 64);

        float ns = tanhf(c) + nz;      // all lanes compute; only 0,1 used
        if (lane < 2) {
            u64 pk = ((u64)(unsigned)t << 32) | (u64)__float_as_uint(ns);
            __hip_atomic_store(&dbuf[row0 + lane], pk, __ATOMIC_RELAXED,
                               __HIP_MEMORY_SCOPE_AGENT);
        }
    }
}

__global__ void epilogue(const u64* __restrict__ statebuf,
                         const float* __restrict__ inputs,
                         const float* __restrict__ outputs,
                         const float* __restrict__ w_out,
                         float* __restrict__ out)
{
    const u64* sb = statebuf + ((TT - 1) & 1) * NRES;   // state(4095) in buf 1
    const int tid  = threadIdx.x;   // 1024 threads = 16 waves
    const int wave = tid >> 6;
    const int lane = tid & 63;

    float acc = 0.0f;
#pragma unroll
    for (int k = 0; k < NRES / 64; ++k) {
        int r = lane + 64 * k;
        acc = fmaf(__uint_as_float((unsigned)sb[r]), w_out[r * NOUT + wave], acc);
    }
#pragma unroll
    for (int off = 32; off; off >>= 1) acc += __shfl_xor(acc, off, 64);
    if (lane == 0) out[wave] = acc;

    for (int i = tid; i < NRES; i += 1024)
        out[NOUT + i] = __uint_as_float((unsigned)sb[i]);
    if (tid < NIN)  out[NOUT + NRES + tid]       = inputs[(TT - 1) * NIN + tid];
    if (tid < NOUT) out[NOUT + NRES + NIN + tid] = outputs[(TT - 2) * NOUT + tid];
}

extern "C" void kernel_launch(void* const* d_in, const int* in_sizes, int n_in,
                              void* d_out, int out_size, void* d_ws, size_t ws_size,
                              hipStream_t stream) {
    const float* inputs  = (const float*)d_in[0];   // (4096, 64)
    const float* outputs = (const float*)d_in[1];   // (4096, 16)
    const float* noise   = (const float*)d_in[2];   // (4096, 2048)
    const float* w       = (const float*)d_in[3];   // (2048, 2048)
    const float* w_in    = (const float*)d_in[4];   // (2048, 64)
    const float* w_feedb = (const float*)d_in[5];   // (2048, 16)
    const float* w_out   = (const float*)d_in[6];   // (2048, 16)
    float* out = (float*)d_out;                     // 16 + 2128 floats

    u64* statebuf = (u64*)d_ws;                     // 2 * 2048 u64 = 32 KB

    init_ws<<<dim3(8), dim3(512), 0, stream>>>(statebuf);
    reservoir_run<<<dim3(GWG), dim3(BTH), 0, stream>>>(inputs, outputs, noise,
                                                       w, w_in, w_feedb, statebuf);
    epilogue<<<dim3(1), dim3(1024), 0, stream>>>(statebuf, inputs, outputs, w_out, out);
}